// Round 9
// baseline (330.614 us; speedup 1.0000x reference)
//
#include <hip/hip_runtime.h>

#define N_NODES 100000
#define N_EDGES 1600000
#define D 64
#define NG 98                 // coarse groups of 1024 nodes
#define NB2 512               // blocks for countA / scatterA
#define EPB2 (N_EDGES / NB2)  // 3125 edges per block
#define AST 68                // padded LDS row stride (bank-conflict-free)

// -------- K0: x (fp32) -> xh (bf16, RNE) --------
__device__ __forceinline__ unsigned bf16rne(float f) {
    unsigned u = __float_as_uint(f);
    return (u + 0x7FFFu + ((u >> 16) & 1u)) >> 16;
}
__global__ __launch_bounds__(256) void tobf16_kernel(const float* __restrict__ x,
                                                     ushort* __restrict__ xh) {
    int i = (blockIdx.x * 256 + threadIdx.x) * 8;
    float4 a = *(const float4*)(x + i);
    float4 b = *(const float4*)(x + i + 4);
    uint4 o;
    o.x = bf16rne(a.x) | (bf16rne(a.y) << 16);
    o.y = bf16rne(a.z) | (bf16rne(a.w) << 16);
    o.z = bf16rne(b.x) | (bf16rne(b.y) << 16);
    o.w = bf16rne(b.z) | (bf16rne(b.w) << 16);
    *(uint4*)(xh + i) = o;
}

// -------- K1: per-block coarse counts + global totals --------
__global__ __launch_bounds__(256) void countA_kernel(const int* __restrict__ row,
                                                     const int* __restrict__ col,
                                                     int* __restrict__ locC,
                                                     int* __restrict__ locR,
                                                     int* __restrict__ gtotC,
                                                     int* __restrict__ gtotR) {
    __shared__ int cC[NG];
    __shared__ int cR[NG];
    int t = threadIdx.x;
    if (t < NG) { cC[t] = 0; cR[t] = 0; }
    __syncthreads();
    int base = blockIdx.x * EPB2;
    for (int i = t; i < EPB2; i += 256) {
        atomicAdd(&cC[col[base + i] >> 10], 1);
        atomicAdd(&cR[row[base + i] >> 10], 1);
    }
    __syncthreads();
    if (t < NG) {
        locC[blockIdx.x * NG + t] = cC[t];
        locR[blockIdx.x * NG + t] = cR[t];
        atomicAdd(&gtotC[t], cC[t]);
        atomicAdd(&gtotR[t], cR[t]);
    }
}

// -------- K2: exclusive scan of the 98 group totals (both sides) --------
__global__ __launch_bounds__(128) void scanG_kernel(const int* __restrict__ gtotC,
                                                    const int* __restrict__ gtotR,
                                                    int* __restrict__ gstartC,
                                                    int* __restrict__ gcurC,
                                                    int* __restrict__ gstartR,
                                                    int* __restrict__ gcurR) {
    __shared__ int lds[128];
    int t = threadIdx.x;
    int v = (t < NG) ? gtotC[t] : 0;
    lds[t] = v;
    __syncthreads();
    for (int off = 1; off < 128; off <<= 1) {
        int u = (t >= off) ? lds[t - off] : 0;
        __syncthreads();
        lds[t] += u;
        __syncthreads();
    }
    if (t < NG) { int e = lds[t] - v; gstartC[t] = e; gcurC[t] = e; }
    __syncthreads();
    int v2 = (t < NG) ? gtotR[t] : 0;
    lds[t] = v2;
    __syncthreads();
    for (int off = 1; off < 128; off <<= 1) {
        int u = (t >= off) ? lds[t - off] : 0;
        __syncthreads();
        lds[t] += u;
        __syncthreads();
    }
    if (t < NG) { int e = lds[t] - v2; gstartR[t] = e; gcurR[t] = e; }
}

// -------- K3: scatter to coarse groups; blocks claim contiguous windows ----
// arec = (row | colin<<17, w fp32)     8B, col-coarse order
// rrec = (bits(w) & ~1023) | (row&1023) 4B, row-coarse order
__global__ __launch_bounds__(256) void scatterA_kernel(const int* __restrict__ row,
                                                       const int* __restrict__ col,
                                                       const float* __restrict__ w,
                                                       const int* __restrict__ locC,
                                                       const int* __restrict__ locR,
                                                       int* __restrict__ gcurC,
                                                       int* __restrict__ gcurR,
                                                       int2* __restrict__ arecs,
                                                       unsigned* __restrict__ rrecs) {
    __shared__ int curC[NG];
    __shared__ int curR[NG];
    int t = threadIdx.x;
    if (t < NG) {
        curC[t] = atomicAdd(&gcurC[t], locC[blockIdx.x * NG + t]);
        curR[t] = atomicAdd(&gcurR[t], locR[blockIdx.x * NG + t]);
    }
    __syncthreads();
    int base = blockIdx.x * EPB2;
    for (int i = t; i < EPB2; i += 256) {
        int r = row[base + i];
        int c = col[base + i];
        float we = w[base + i];
        int pC = atomicAdd(&curC[c >> 10], 1);
        arecs[pC] = make_int2(r | ((c & 1023) << 17), __float_as_int(we));
        int pR = atomicAdd(&curR[r >> 10], 1);
        rrecs[pR] = (__float_as_uint(we) & ~1023u) | (unsigned)(r & 1023);
    }
}

// -------- K4: per coarse row-group degree reduction -> dinv --------
__global__ __launch_bounds__(512) void deg_kernel(const unsigned* __restrict__ rrecs,
                                                  const int* __restrict__ gstartR,
                                                  const int* __restrict__ gtotR,
                                                  float* __restrict__ dinv) {
    __shared__ float acc[1024];
    int t = threadIdx.x;
    int g = blockIdx.x;
    acc[t] = 0.f;
    acc[t + 512] = 0.f;
    __syncthreads();
    int s = gstartR[g];
    int cnt = gtotR[g];
    for (int i = t; i < cnt; i += 512) {
        unsigned v = rrecs[s + i];
        atomicAdd(&acc[v & 1023u], __uint_as_float(v & ~1023u));
    }
    __syncthreads();
    int n = g * 1024 + t;
    if (n < N_NODES) { float d = acc[t]; dinv[n] = d > 0.f ? rsqrtf(d) : 0.f; }
    n += 512;
    if (n < N_NODES) { float d = acc[t + 512]; dinv[n] = d > 0.f ? rsqrtf(d) : 0.f; }
}

// -------- K5: sort each coarse group by exact node; emit 4B crecs + nmeta --
// crec = row<<15 | q15(w * dinv[row])   (coeff = w/sqrt(deg) < 1 always)
__global__ __launch_bounds__(512) void scatterB_kernel(const int2* __restrict__ arecs,
                                                       const int* __restrict__ gstartC,
                                                       const int* __restrict__ gtotC,
                                                       const float* __restrict__ dinv,
                                                       unsigned* __restrict__ crecs,
                                                       int2* __restrict__ nmeta) {
    __shared__ int cnt1024[1024];
    __shared__ int cur1024[1024];
    __shared__ int wsum[8];
    int t = threadIdx.x;
    int g = blockIdx.x;
    cnt1024[t] = 0;
    cnt1024[t + 512] = 0;
    __syncthreads();
    int s = gstartC[g];
    int cnt = gtotC[g];
    for (int i = t; i < cnt; i += 512)
        atomicAdd(&cnt1024[(arecs[s + i].x >> 17) & 1023], 1);
    __syncthreads();
    // exclusive scan of 1024 via pairs: thread t owns elements 2t, 2t+1
    int a0 = cnt1024[2 * t];
    int a1 = cnt1024[2 * t + 1];
    int pair = a0 + a1;
    int lane = t & 63, wid = t >> 6;
    int inc = pair;
    #pragma unroll
    for (int d = 1; d < 64; d <<= 1) {
        int u = __shfl_up(inc, d, 64);
        if (lane >= d) inc += u;
    }
    if (lane == 63) wsum[wid] = inc;
    __syncthreads();
    if (t == 0) {
        int a = 0;
        #pragma unroll
        for (int i = 0; i < 8; ++i) { int v = wsum[i]; wsum[i] = a; a += v; }
    }
    __syncthreads();
    int excl = wsum[wid] + inc - pair;
    cur1024[2 * t] = excl;
    cur1024[2 * t + 1] = excl + a0;
    int n = g * 1024 + 2 * t;
    if (n < N_NODES)     nmeta[n]     = make_int2(s + excl, a0);
    if (n + 1 < N_NODES) nmeta[n + 1] = make_int2(s + excl + a0, a1);
    __syncthreads();
    // place, folding dinv[row] + q15 quantization
    for (int i = t; i < cnt; i += 512) {
        int2 a = arecs[s + i];
        int r = a.x & 0x1FFFF;
        int colin = (a.x >> 17) & 1023;
        float cf = __int_as_float(a.y) * dinv[r];
        unsigned q = (unsigned)min(32767, (int)(cf * 32768.f + 0.5f));
        int p = atomicAdd(&cur1024[colin], 1);
        crecs[s + p] = ((unsigned)r << 15) | q;
    }
}

#define FMA_BF16(cc, u)                                                        \
    acc0.x += cc * __uint_as_float((u).x << 16);                               \
    acc0.y += cc * __uint_as_float((u).x & 0xFFFF0000u);                       \
    acc0.z += cc * __uint_as_float((u).y << 16);                               \
    acc0.w += cc * __uint_as_float((u).y & 0xFFFF0000u);                       \
    acc1.x += cc * __uint_as_float((u).z << 16);                               \
    acc1.y += cc * __uint_as_float((u).z & 0xFFFF0000u);                       \
    acc1.z += cc * __uint_as_float((u).w << 16);                               \
    acc1.w += cc * __uint_as_float((u).w & 0xFFFF0000u);

// -------- K6: streaming per-node gather (no sort, no barriers) + matmul ----
// Block = 32 nodes x 8 lanes. Records are node-contiguous; 8 lanes vector-
// load 8 crecs, shfl-broadcast each, 8 independent bf16-row loads in flight.
__global__ __launch_bounds__(256) void gather_out_kernel(
        const unsigned* __restrict__ crecs, const int2* __restrict__ nmeta,
        const float* __restrict__ dinv,
        const ushort* __restrict__ xh, const float* __restrict__ x,
        const float* __restrict__ W0, const float* __restrict__ W1,
        const float* __restrict__ bias, float* __restrict__ out) {
    __shared__ float xs[32 * AST];
    __shared__ float ts[32 * AST];
    int tid = threadIdx.x;
    int b = blockIdx.x;
    int n0 = b * 32;
    int g = tid >> 3;        // node within block
    int j = tid & 7;         // lane owns features 8j..8j+7
    int n = n0 + g;

    int2 meta = nmeta[n];
    int s = meta.x;
    int cnt = meta.y;
    const unsigned* cr = crecs + s;
    const ushort* xhj = xh + (j << 3);

    float4 acc0 = make_float4(0.f, 0.f, 0.f, 0.f);
    float4 acc1 = make_float4(0.f, 0.f, 0.f, 0.f);

    for (int k = 0; k < cnt; k += 8) {
        int kj = k + j;
        unsigned myrec = (kj < cnt) ? cr[kj] : 0u;   // rec 0 -> coeff 0 (safe)
        #pragma unroll
        for (int q = 0; q < 8; ++q) {
            unsigned rec = __shfl(myrec, q, 8);
            float cc = (float)(rec & 32767u) * (1.f / 32768.f);
            uint4 u = *(const uint4*)(xhj + ((size_t)(rec >> 15) << 6));
            FMA_BF16(cc, u);
        }
    }

    // Phase C: ts = -dinv[n]*acc, stage xs (fp32), matmul epilogue.
    float dn = -dinv[n];
    float* tp = ts + g * AST + (j << 3);
    *(float4*)tp       = make_float4(dn * acc0.x, dn * acc0.y, dn * acc0.z, dn * acc0.w);
    *(float4*)(tp + 4) = make_float4(dn * acc1.x, dn * acc1.y, dn * acc1.z, dn * acc1.w);
    for (int i = tid; i < 512; i += 256) {           // 512 float4 = 32x64 floats
        int nn = i >> 4;
        int kk = (i & 15) << 2;
        *(float4*)&xs[nn * AST + kk] = *(const float4*)(x + (size_t)n0 * D + i * 4);
    }
    __syncthreads();

    int jl = j << 3;
    float4 o0 = *(const float4*)(bias + jl);
    float4 o1 = *(const float4*)(bias + jl + 4);
    for (int k = 0; k < D; k += 4) {
        float4 av = *(const float4*)&xs[g * AST + k];
        float4 tv = *(const float4*)&ts[g * AST + k];
        #pragma unroll
        for (int u = 0; u < 4; ++u) {
            float a = (u == 0) ? av.x : (u == 1) ? av.y : (u == 2) ? av.z : av.w;
            float t = (u == 0) ? tv.x : (u == 1) ? tv.y : (u == 2) ? tv.z : tv.w;
            const float4 w00 = *(const float4*)(W0 + (size_t)(k + u) * D + jl);
            const float4 w01 = *(const float4*)(W0 + (size_t)(k + u) * D + jl + 4);
            const float4 w10 = *(const float4*)(W1 + (size_t)(k + u) * D + jl);
            const float4 w11 = *(const float4*)(W1 + (size_t)(k + u) * D + jl + 4);
            o0.x += a * w00.x + t * w10.x;
            o0.y += a * w00.y + t * w10.y;
            o0.z += a * w00.z + t * w10.z;
            o0.w += a * w00.w + t * w10.w;
            o1.x += a * w01.x + t * w11.x;
            o1.y += a * w01.y + t * w11.y;
            o1.z += a * w01.z + t * w11.z;
            o1.w += a * w01.w + t * w11.w;
        }
    }
    float* op = out + (size_t)n * D + jl;
    *(float4*)op       = o0;
    *(float4*)(op + 4) = o1;
}

extern "C" void kernel_launch(void* const* d_in, const int* in_sizes, int n_in,
                              void* d_out, int out_size, void* d_ws, size_t ws_size,
                              hipStream_t stream) {
    const float* x    = (const float*)d_in[0];
    const int*   eidx = (const int*)d_in[1];   // [2, E]: row then col
    const float* ew   = (const float*)d_in[2];
    const float* W0   = (const float*)d_in[3];
    const float* W1   = (const float*)d_in[4];
    const float* b    = (const float*)d_in[5];
    float* out = (float*)d_out;

    const int* row = eidx;
    const int* col = eidx + N_EDGES;

    // Workspace layout (4B words). crecs aliases rrecs (rrecs dead after deg).
    // Total ~= 33.6 MB.
    int*      base    = (int*)d_ws;
    int2*     arecs   = (int2*)base;                            // 2E words
    unsigned* rrecs   = (unsigned*)(base + 2 * (size_t)N_EDGES); // E words
    unsigned* crecs   = rrecs;                                   // alias (E words)
    ushort*   xh      = (ushort*)(base + 3 * (size_t)N_EDGES);   // N*D ushort = 3.2M w
    float*    dinv    = (float*)(base + 3 * (size_t)N_EDGES + (size_t)N_NODES * D / 2); // N
    int2*     nmeta   = (int2*)(dinv + N_NODES);                 // 2N words
    int*      locC    = (int*)(nmeta + N_NODES);                 // NB2*NG
    int*      locR    = locC + (size_t)NB2 * NG;                 // NB2*NG
    int*      gtotC   = locR + (size_t)NB2 * NG;                 // NG
    int*      gtotR   = gtotC + NG;                              // NG
    int*      gstartC = gtotR + NG;                              // NG
    int*      gcurC   = gstartC + NG;                            // NG
    int*      gstartR = gcurC + NG;                              // NG
    int*      gcurR   = gstartR + NG;                            // NG

    hipMemsetAsync(gtotC, 0, 2 * NG * sizeof(int), stream);

    tobf16_kernel  <<<N_NODES * D / (256 * 8), 256, 0, stream>>>(x, xh);
    countA_kernel  <<<NB2, 256, 0, stream>>>(row, col, locC, locR, gtotC, gtotR);
    scanG_kernel   <<<1, 128, 0, stream>>>(gtotC, gtotR, gstartC, gcurC, gstartR, gcurR);
    scatterA_kernel<<<NB2, 256, 0, stream>>>(row, col, ew, locC, locR,
                                             gcurC, gcurR, arecs, rrecs);
    deg_kernel     <<<NG, 512, 0, stream>>>(rrecs, gstartR, gtotR, dinv);
    scatterB_kernel<<<NG, 512, 0, stream>>>(arecs, gstartC, gtotC, dinv, crecs, nmeta);
    gather_out_kernel<<<N_NODES / 32, 256, 0, stream>>>(crecs, nmeta, dinv,
                                                        xh, x, W0, W1, b, out);
}